// Round 1
// baseline (1054.939 us; speedup 1.0000x reference)
//
#include <hip/hip_runtime.h>
#include <math.h>

#define NTOK 65536
#define DIMD 128
#define KCB  2048
#define BM   128
#define BN   128
#define DCH  32

constexpr float SCALE = 200.0f;  // 2 / temperature(0.01)

// ---------------- helpers ----------------

__device__ __forceinline__ float block_reduce4(float v, volatile float* sm, int tid) {
  #pragma unroll
  for (int off = 32; off; off >>= 1) v += __shfl_xor(v, off, 64);
  __syncthreads();
  if ((tid & 63) == 0) sm[tid >> 6] = v;
  __syncthreads();
  float r = sm[0] + sm[1] + sm[2] + sm[3];
  __syncthreads();
  return r;
}

// ---------------- small kernels ----------------

__global__ __launch_bounds__(256) void k_zero(float* __restrict__ avgp, float* __restrict__ t1,
                                              float* __restrict__ cnt) {
  const int i = blockIdx.x * 256 + threadIdx.x;
  if (i < KCB) { avgp[i] = 0.0f; cnt[i] = 0.0f; }
  if (i == 0) t1[0] = 0.0f;
}

__global__ __launch_bounds__(256) void k_rownorm(const float* __restrict__ x, const float* __restrict__ mask,
                                                 float* __restrict__ scaleInv) {
  const int wid = (blockIdx.x * 256 + threadIdx.x) >> 6;
  const int lane = threadIdx.x & 63;
  if (wid >= NTOK) return;
  const float add = (1.0f - mask[wid]) * 1e-6f;
  const float2 v = *(const float2*)(x + (size_t)wid * DIMD + lane * 2);
  const float a0 = v.x + add, a1 = v.y + add;
  float ss = a0 * a0 + a1 * a1;
  #pragma unroll
  for (int off = 32; off; off >>= 1) ss += __shfl_xor(ss, off, 64);
  if (lane == 0) scaleInv[wid] = 1.0f / fmaxf(sqrtf(ss), 1e-6f);
}

__global__ __launch_bounds__(256) void k_gather(const float* __restrict__ cb, const float* __restrict__ mask,
                                                const int* __restrict__ rowIdx, float* __restrict__ outQ,
                                                float* __restrict__ outCnt, float* __restrict__ outEnc) {
  const int wid = (blockIdx.x * 256 + threadIdx.x) >> 6;
  const int lane = threadIdx.x & 63;
  if (wid >= NTOK) return;
  const int idx = rowIdx[wid];
  const float2 v = *(const float2*)(cb + (size_t)idx * DIMD + lane * 2);
  *(float2*)(outQ + (size_t)wid * DIMD + lane * 2) = v;
  if (lane == 0) {
    atomicAdd(&outCnt[idx], mask[wid]);
    outEnc[wid] = (float)idx;
  }
}

// ---------------- GEMM pass 1: per-row max / argmax / Z ----------------

__global__ __launch_bounds__(256) void k_pass1(const float* __restrict__ x, const float* __restrict__ mask,
                                               const float* __restrict__ cb, const float* __restrict__ scaleInv,
                                               float* __restrict__ rowMax, float* __restrict__ rowZ,
                                               int* __restrict__ rowIdx) {
  __shared__ __align__(16) float As[DCH][BM];
  __shared__ __align__(16) float Bs[DCH][BN];
  const int tid = threadIdx.x;
  const int row0 = blockIdx.x * BM;
  const int tx = tid & 15, ty = tid >> 4;

  // per-thread staging rows: r = (tid>>3) + it*32 — preload row scale/add
  const int rstage = tid >> 3;
  float sadd[4], ssc[4];
  #pragma unroll
  for (int it = 0; it < 4; ++it) {
    const int row = row0 + rstage + it * 32;
    sadd[it] = (1.0f - mask[row]) * 1e-6f;
    ssc[it] = scaleInv[row];
  }

  float runmax[8], runsum[8], bestv[8];
  int bestk[8];
  #pragma unroll
  for (int i = 0; i < 8; ++i) { runmax[i] = -1e30f; runsum[i] = 0.0f; bestv[i] = -1e30f; bestk[i] = 0; }

  for (int kt = 0; kt < KCB; kt += BN) {
    float acc[8][8];
    #pragma unroll
    for (int i = 0; i < 8; ++i)
      #pragma unroll
      for (int j = 0; j < 8; ++j) acc[i][j] = 0.0f;

    for (int dc = 0; dc < DIMD; dc += DCH) {
      __syncthreads();
      {
        const int fi = tid & 7, d0 = fi * 4, xs = fi << 3;
        #pragma unroll
        for (int it = 0; it < 4; ++it) {
          const int r = rstage + it * 32;
          const int c = r ^ xs;
          const float4 va = *(const float4*)(x + (size_t)(row0 + r) * DIMD + dc + d0);
          As[d0 + 0][c] = (va.x + sadd[it]) * ssc[it];
          As[d0 + 1][c] = (va.y + sadd[it]) * ssc[it];
          As[d0 + 2][c] = (va.z + sadd[it]) * ssc[it];
          As[d0 + 3][c] = (va.w + sadd[it]) * ssc[it];
          const float4 vb = *(const float4*)(cb + (size_t)(kt + r) * DIMD + dc + d0);
          Bs[d0 + 0][c] = vb.x; Bs[d0 + 1][c] = vb.y; Bs[d0 + 2][c] = vb.z; Bs[d0 + 3][c] = vb.w;
        }
      }
      __syncthreads();
      #pragma unroll 8
      for (int dl = 0; dl < DCH; ++dl) {
        const int xs = (dl >> 2) << 3;
        const int ca = (ty * 8) ^ xs;
        const int cbx = (tx * 8) ^ xs;
        const float4 a0 = *(const float4*)&As[dl][ca];
        const float4 a1 = *(const float4*)&As[dl][ca + 4];
        const float4 b0 = *(const float4*)&Bs[dl][cbx];
        const float4 b1 = *(const float4*)&Bs[dl][cbx + 4];
        const float av[8] = {a0.x, a0.y, a0.z, a0.w, a1.x, a1.y, a1.z, a1.w};
        const float bv[8] = {b0.x, b0.y, b0.z, b0.w, b1.x, b1.y, b1.z, b1.w};
        #pragma unroll
        for (int i = 0; i < 8; ++i)
          #pragma unroll
          for (int j = 0; j < 8; ++j)
            acc[i][j] = fmaf(av[i], bv[j], acc[i][j]);
      }
    }
    // online stats for this k-tile
    #pragma unroll
    for (int i = 0; i < 8; ++i) {
      float tmax = acc[i][0];
      #pragma unroll
      for (int j = 1; j < 8; ++j) tmax = fmaxf(tmax, acc[i][j]);
      #pragma unroll
      for (int j = 0; j < 8; ++j) {
        const int kk = kt + tx * 8 + j;
        const bool better = acc[i][j] > bestv[i];
        bestv[i] = better ? acc[i][j] : bestv[i];
        bestk[i] = better ? kk : bestk[i];
      }
      const float nm = fmaxf(runmax[i], tmax);
      runsum[i] *= __expf((runmax[i] - nm) * SCALE);
      runmax[i] = nm;
      float e = 0.0f;
      #pragma unroll
      for (int j = 0; j < 8; ++j) e += __expf((acc[i][j] - nm) * SCALE);
      runsum[i] += e;
    }
  }
  // reduce across the 16 tx lanes (consecutive lanes within the wave)
  #pragma unroll
  for (int i = 0; i < 8; ++i) {
    float rm = runmax[i], rs = runsum[i], bv = bestv[i];
    int bk = bestk[i];
    #pragma unroll
    for (int off = 8; off; off >>= 1) {
      const float om = __shfl_xor(rm, off, 64);
      const float os = __shfl_xor(rs, off, 64);
      const float ov = __shfl_xor(bv, off, 64);
      const int   ok = __shfl_xor(bk, off, 64);
      const float nm = fmaxf(rm, om);
      rs = rs * __expf((rm - nm) * SCALE) + os * __expf((om - nm) * SCALE);
      rm = nm;
      const bool take = (ov > bv) || ((ov == bv) && (ok < bk));
      bv = take ? ov : bv;
      bk = take ? ok : bk;
    }
    if (tx == 0) {
      const int row = row0 + ty * 8 + i;
      rowMax[row] = rm;
      rowZ[row] = rs;
      rowIdx[row] = bk;
    }
  }
}

// ---------------- GEMM pass 2: avg_probs column sums + sample-entropy ----------------

__global__ __launch_bounds__(256) void k_pass2(const float* __restrict__ x, const float* __restrict__ mask,
                                               const float* __restrict__ cb, const float* __restrict__ scaleInv,
                                               const float* __restrict__ rowMax, const float* __restrict__ rowZ,
                                               float* __restrict__ avgp, float* __restrict__ t1g) {
  __shared__ __align__(16) float As[DCH][BM];
  __shared__ __align__(16) float Bs[DCH][BN];
  __shared__ float ap[KCB];
  __shared__ float sm4[4];
  const int tid = threadIdx.x;
  const int row0 = blockIdx.x * BM;
  const int tx = tid & 15, ty = tid >> 4;

  for (int i = tid; i < KCB; i += 256) ap[i] = 0.0f;

  const int rstage = tid >> 3;
  float sadd[4], ssc[4];
  #pragma unroll
  for (int it = 0; it < 4; ++it) {
    const int row = row0 + rstage + it * 32;
    sadd[it] = (1.0f - mask[row]) * 1e-6f;
    ssc[it] = scaleInv[row];
  }

  float mrow[8], zinv[8], mskr[8];
  #pragma unroll
  for (int i = 0; i < 8; ++i) {
    const int row = row0 + ty * 8 + i;
    mrow[i] = rowMax[row];
    zinv[i] = 1.0f / rowZ[row];
    mskr[i] = mask[row];
  }
  float t1 = 0.0f;

  for (int kt = 0; kt < KCB; kt += BN) {
    float acc[8][8];
    #pragma unroll
    for (int i = 0; i < 8; ++i)
      #pragma unroll
      for (int j = 0; j < 8; ++j) acc[i][j] = 0.0f;

    for (int dc = 0; dc < DIMD; dc += DCH) {
      __syncthreads();
      {
        const int fi = tid & 7, d0 = fi * 4, xs = fi << 3;
        #pragma unroll
        for (int it = 0; it < 4; ++it) {
          const int r = rstage + it * 32;
          const int c = r ^ xs;
          const float4 va = *(const float4*)(x + (size_t)(row0 + r) * DIMD + dc + d0);
          As[d0 + 0][c] = (va.x + sadd[it]) * ssc[it];
          As[d0 + 1][c] = (va.y + sadd[it]) * ssc[it];
          As[d0 + 2][c] = (va.z + sadd[it]) * ssc[it];
          As[d0 + 3][c] = (va.w + sadd[it]) * ssc[it];
          const float4 vb = *(const float4*)(cb + (size_t)(kt + r) * DIMD + dc + d0);
          Bs[d0 + 0][c] = vb.x; Bs[d0 + 1][c] = vb.y; Bs[d0 + 2][c] = vb.z; Bs[d0 + 3][c] = vb.w;
        }
      }
      __syncthreads();
      #pragma unroll 8
      for (int dl = 0; dl < DCH; ++dl) {
        const int xs = (dl >> 2) << 3;
        const int ca = (ty * 8) ^ xs;
        const int cbx = (tx * 8) ^ xs;
        const float4 a0 = *(const float4*)&As[dl][ca];
        const float4 a1 = *(const float4*)&As[dl][ca + 4];
        const float4 b0 = *(const float4*)&Bs[dl][cbx];
        const float4 b1 = *(const float4*)&Bs[dl][cbx + 4];
        const float av[8] = {a0.x, a0.y, a0.z, a0.w, a1.x, a1.y, a1.z, a1.w};
        const float bv[8] = {b0.x, b0.y, b0.z, b0.w, b1.x, b1.y, b1.z, b1.w};
        #pragma unroll
        for (int i = 0; i < 8; ++i)
          #pragma unroll
          for (int j = 0; j < 8; ++j)
            acc[i][j] = fmaf(av[i], bv[j], acc[i][j]);
      }
    }
    // probabilities -> column sums + entropy partial
    float colsum[8];
    #pragma unroll
    for (int j = 0; j < 8; ++j) colsum[j] = 0.0f;
    #pragma unroll
    for (int i = 0; i < 8; ++i) {
      #pragma unroll
      for (int j = 0; j < 8; ++j) {
        const float t = acc[i][j] - mrow[i];
        const float p = __expf(t * SCALE) * zinv[i];
        const float pm = p * mskr[i];
        colsum[j] += pm;
        t1 = fmaf(pm, t, t1);
      }
    }
    // reduce the 4 ty-subgroups within each wave, then LDS-accumulate
    #pragma unroll
    for (int j = 0; j < 8; ++j) {
      colsum[j] += __shfl_xor(colsum[j], 16, 64);
      colsum[j] += __shfl_xor(colsum[j], 32, 64);
    }
    if ((tid & 63) < 16) {
      #pragma unroll
      for (int j = 0; j < 8; ++j)
        atomicAdd(&ap[kt + (tid & 15) * 8 + j], colsum[j]);
    }
  }
  __syncthreads();
  for (int i = tid; i < KCB; i += 256) atomicAdd(&avgp[i], ap[i]);
  #pragma unroll
  for (int off = 32; off; off >>= 1) t1 += __shfl_xor(t1, off, 64);
  if ((tid & 63) == 0) sm4[tid >> 6] = t1;
  __syncthreads();
  if (tid == 0) atomicAdd(t1g, (sm4[0] + sm4[1] + sm4[2] + sm4[3]) * SCALE);
}

// ---------------- finalize scalars ----------------

__global__ __launch_bounds__(256) void k_final(const float* __restrict__ mask, const float* __restrict__ rowMax,
                                               const float* __restrict__ rowZ, const float* __restrict__ avgp,
                                               const float* __restrict__ t1g, float* __restrict__ out3) {
  __shared__ float sm[4];
  const int tid = threadIdx.x;
  float msum = 0.f, slogz = 0.f, slat = 0.f;
  for (int n = tid; n < NTOK; n += 256) {
    const float mk = mask[n];
    msum += mk;
    slogz = fmaf(mk, __logf(rowZ[n]), slogz);
    slat  = fmaf(mk, 2.0f - 2.0f * rowMax[n], slat);
  }
  msum = block_reduce4(msum, sm, tid);
  slogz = block_reduce4(slogz, sm, tid);
  slat = block_reduce4(slat, sm, tid);
  float ae = 0.f;
  for (int k2 = tid; k2 < KCB; k2 += 256) {
    const float a = avgp[k2] / msum;
    ae += a * __logf(a + 1e-5f);
  }
  ae = block_reduce4(ae, sm, tid);
  if (tid == 0) {
    const float t1 = t1g[0];
    const float sample_entropy = (slogz - t1) / msum;  // -(sum p log p)/msum
    const float entropy = sample_entropy + ae;         // sample - avg, avg = -ae
    const float lat = slat / (msum + 1e-6f);
    out3[0] = lat;
    out3[1] = lat;
    out3[2] = entropy;
  }
}

// ---------------- launcher ----------------

extern "C" void kernel_launch(void* const* d_in, const int* in_sizes, int n_in,
                              void* d_out, int out_size, void* d_ws, size_t ws_size,
                              hipStream_t stream) {
  const float* x = (const float*)d_in[0];
  const float* mask = (const float*)d_in[1];
  const float* cb = (const float*)d_in[2];

  float* out = (float*)d_out;
  float* outQ = out;
  float* out3 = out + (size_t)NTOK * DIMD;
  float* outCnt = out3 + 3;
  float* outEnc = outCnt + KCB;

  float* ws = (float*)d_ws;
  float* scaleInv = ws;               // N
  float* rowMax = ws + NTOK;          // N
  float* rowZ = ws + 2 * NTOK;        // N
  int* rowIdx = (int*)(ws + 3 * NTOK);// N
  float* avgp = ws + 4 * NTOK;        // K
  float* t1g = avgp + KCB;            // 1

  k_zero<<<(KCB + 255) / 256, 256, 0, stream>>>(avgp, t1g, outCnt);
  k_rownorm<<<(NTOK * 64) / 256, 256, 0, stream>>>(x, mask, scaleInv);
  k_pass1<<<NTOK / BM, 256, 0, stream>>>(x, mask, cb, scaleInv, rowMax, rowZ, rowIdx);
  k_pass2<<<NTOK / BM, 256, 0, stream>>>(x, mask, cb, scaleInv, rowMax, rowZ, avgp, t1g);
  k_gather<<<(NTOK * 64) / 256, 256, 0, stream>>>(cb, mask, rowIdx, outQ, outCnt, outEnc);
  k_final<<<1, 256, 0, stream>>>(mask, rowMax, rowZ, avgp, t1g, out3);
}

// Round 2
// 614.351 us; speedup vs baseline: 1.7172x; 1.7172x over previous
//
#include <hip/hip_runtime.h>
#include <math.h>

#define NTOK 65536
#define DIMD 128
#define KCB  2048

typedef unsigned short u16;
typedef __attribute__((ext_vector_type(8))) unsigned short u16x8;
typedef __attribute__((ext_vector_type(8))) __bf16 bf16x8;
typedef __attribute__((ext_vector_type(4))) float f32x4;

union U8 { u16x8 u; bf16x8 b; };

__device__ __forceinline__ u16 f2bf(float f) {
  union { float f; unsigned u; } c; c.f = f;
  unsigned r = c.u + 0x7FFFu + ((c.u >> 16) & 1u);
  return (u16)(r >> 16);
}
__device__ __forceinline__ float bf2f(u16 h) {
  union { unsigned u; float f; } c; c.u = ((unsigned)h) << 16;
  return c.f;
}

__device__ __forceinline__ float block_reduce4(float v, volatile float* sm, int tid) {
  #pragma unroll
  for (int off = 32; off; off >>= 1) v += __shfl_xor(v, off, 64);
  __syncthreads();
  if ((tid & 63) == 0) sm[tid >> 6] = v;
  __syncthreads();
  float r = sm[0] + sm[1] + sm[2] + sm[3];
  __syncthreads();
  return r;
}

// ---------------- small kernels ----------------

__global__ __launch_bounds__(256) void k_zero(float* __restrict__ avgp, float* __restrict__ t1,
                                              float* __restrict__ cnt) {
  const int i = blockIdx.x * 256 + threadIdx.x;
  if (i < KCB) { avgp[i] = 0.0f; cnt[i] = 0.0f; }
  if (i == 0) t1[0] = 0.0f;
}

// normalize rows of x and emit bf16 split halves (one wave per row)
__global__ __launch_bounds__(256) void k_prepx(const float* __restrict__ x, const float* __restrict__ mask,
                                               float* __restrict__ scaleInv, u16* __restrict__ xh,
                                               u16* __restrict__ xl) {
  const int wid = (blockIdx.x * 256 + threadIdx.x) >> 6;
  const int lane = threadIdx.x & 63;
  if (wid >= NTOK) return;
  const float add = (1.0f - mask[wid]) * 1e-6f;
  const float2 v = *(const float2*)(x + (size_t)wid * DIMD + lane * 2);
  const float a0 = v.x + add, a1 = v.y + add;
  float ss = a0 * a0 + a1 * a1;
  #pragma unroll
  for (int off = 32; off; off >>= 1) ss += __shfl_xor(ss, off, 64);
  const float sc = 1.0f / fmaxf(sqrtf(ss), 1e-6f);
  if (lane == 0) scaleInv[wid] = sc;
  const float f0 = a0 * sc, f1 = a1 * sc;
  const u16 h0 = f2bf(f0), h1 = f2bf(f1);
  const u16 g0 = f2bf(f0 - bf2f(h0)), g1 = f2bf(f1 - bf2f(h1));
  union { u16 s[2]; unsigned u; } wh, wl;
  wh.s[0] = h0; wh.s[1] = h1; wl.s[0] = g0; wl.s[1] = g1;
  *(unsigned*)(xh + (size_t)wid * DIMD + lane * 2) = wh.u;
  *(unsigned*)(xl + (size_t)wid * DIMD + lane * 2) = wl.u;
}

// split codebook rows to bf16 halves (one wave per code row)
__global__ __launch_bounds__(256) void k_splitcb(const float* __restrict__ cb, u16* __restrict__ cbh,
                                                 u16* __restrict__ cbl) {
  const int wid = (blockIdx.x * 256 + threadIdx.x) >> 6;
  const int lane = threadIdx.x & 63;
  if (wid >= KCB) return;
  const float2 v = *(const float2*)(cb + (size_t)wid * DIMD + lane * 2);
  const u16 h0 = f2bf(v.x), h1 = f2bf(v.y);
  const u16 g0 = f2bf(v.x - bf2f(h0)), g1 = f2bf(v.y - bf2f(h1));
  union { u16 s[2]; unsigned u; } wh, wl;
  wh.s[0] = h0; wh.s[1] = h1; wl.s[0] = g0; wl.s[1] = g1;
  *(unsigned*)(cbh + (size_t)wid * DIMD + lane * 2) = wh.u;
  *(unsigned*)(cbl + (size_t)wid * DIMD + lane * 2) = wl.u;
}

__global__ __launch_bounds__(256) void k_gather(const float* __restrict__ cb, const float* __restrict__ mask,
                                                const int* __restrict__ rowIdx, float* __restrict__ outQ,
                                                float* __restrict__ outCnt, float* __restrict__ outEnc) {
  const int wid = (blockIdx.x * 256 + threadIdx.x) >> 6;
  const int lane = threadIdx.x & 63;
  if (wid >= NTOK) return;
  const int idx = rowIdx[wid];
  const float2 v = *(const float2*)(cb + (size_t)idx * DIMD + lane * 2);
  *(float2*)(outQ + (size_t)wid * DIMD + lane * 2) = v;
  if (lane == 0) {
    atomicAdd(&outCnt[idx], mask[wid]);
    outEnc[wid] = (float)idx;
  }
}

// exact-f32 argmax rescan for rows whose approx top-2 gap is tiny
__global__ __launch_bounds__(256) void k_refine(const float* __restrict__ x, const float* __restrict__ mask,
                                                const float* __restrict__ cb, const float* __restrict__ scaleInv,
                                                const float* __restrict__ rowV1, const float* __restrict__ rowV2,
                                                const int* __restrict__ rowK1, int* __restrict__ rowIdx) {
  const int wid = (blockIdx.x * 256 + threadIdx.x) >> 6;
  const int lane = threadIdx.x & 63;
  if (wid >= NTOK) return;
  if (rowV1[wid] - rowV2[wid] > 1e-4f) {
    if (lane == 0) rowIdx[wid] = rowK1[wid];
    return;
  }
  const float add = (1.0f - mask[wid]) * 1e-6f;
  const float sc = scaleInv[wid];
  const float2 v = *(const float2*)(x + (size_t)wid * DIMD + lane * 2);
  const float xn0 = (v.x + add) * sc, xn1 = (v.y + add) * sc;
  float best = -1e30f;
  int bidx = 0;
  #pragma unroll 4
  for (int k = 0; k < KCB; ++k) {
    const float2 c = *(const float2*)(cb + (size_t)k * DIMD + lane * 2);
    float d = fmaf(xn0, c.x, xn1 * c.y);
    #pragma unroll
    for (int off = 32; off; off >>= 1) d += __shfl_xor(d, off, 64);
    if (d > best) { best = d; bidx = k; }
  }
  if (lane == 0) rowIdx[wid] = bidx;
}

// ---------------- MFMA pass 1: per-row max / argmax(top2) / Z ----------------

__global__ __launch_bounds__(256, 2) void k_pass1(const u16* __restrict__ xh, const u16* __restrict__ xl,
                                                  const u16* __restrict__ cbh, const u16* __restrict__ cbl,
                                                  float* __restrict__ rowV1, float* __restrict__ rowZ,
                                                  float* __restrict__ rowV2, int* __restrict__ rowK1) {
  __shared__ __align__(16) char Bsmem[65536];
  char* BsHb = Bsmem;
  char* BsLb = Bsmem + 32768;
  const int tid = threadIdx.x;
  const int lane = tid & 63, w = tid >> 6;
  const int l15 = lane & 15, hi = lane >> 4;
  const int row0 = blockIdx.x * 128;

  // staging source offset (inverse-swizzled so that linear LDS dest + swizzled read works)
  const int tbase = ((tid >> 4) << 8) + ((((tid & 15) << 4)) ^ (((tid >> 4) & 7) << 4));

  // A fragments in registers, reused for all 16 k-tiles
  U8 Ah[2][4], Al[2][4];
  #pragma unroll
  for (int mf = 0; mf < 2; ++mf) {
    const size_t arow = (size_t)(row0 + w * 32 + mf * 16 + l15);
    #pragma unroll
    for (int ks = 0; ks < 4; ++ks) {
      const size_t off = arow * DIMD + ks * 32 + hi * 8;
      Ah[mf][ks].u = *(const u16x8*)(xh + off);
      Al[mf][ks].u = *(const u16x8*)(xl + off);
    }
  }
  const int laneAB = l15 * 256;
  int koff[4];
  #pragma unroll
  for (int ks = 0; ks < 4; ++ks) koff[ks] = (ks * 64 + hi * 16) ^ ((l15 & 7) << 4);

  float v1[8], v2[8], rs[8];
  int k1[8];
  #pragma unroll
  for (int r = 0; r < 8; ++r) { v1[r] = -1e30f; v2[r] = -1e30f; rs[r] = 0.0f; k1[r] = 0; }

  for (int kt = 0; kt < 16; ++kt) {
    __syncthreads();
    {
      const char* sH = (const char*)cbh + (size_t)kt * 32768;
      const char* sL = (const char*)cbl + (size_t)kt * 32768;
      #pragma unroll
      for (int i = 0; i < 8; ++i) {
        const int so = i * 4096 + tbase;
        const int ld = i * 4096 + w * 1024;
        __builtin_amdgcn_global_load_lds((const __attribute__((address_space(1))) void*)(sH + so),
                                         (__attribute__((address_space(3))) void*)(BsHb + ld), 16, 0, 0);
        __builtin_amdgcn_global_load_lds((const __attribute__((address_space(1))) void*)(sL + so),
                                         (__attribute__((address_space(3))) void*)(BsLb + ld), 16, 0, 0);
      }
    }
    __syncthreads();

    f32x4 acc[2][8];
    #pragma unroll
    for (int m = 0; m < 2; ++m)
      #pragma unroll
      for (int nf = 0; nf < 8; ++nf) acc[m][nf] = (f32x4){0.f, 0.f, 0.f, 0.f};

    #pragma unroll
    for (int ks = 0; ks < 4; ++ks) {
      const char* pH = BsHb + laneAB + koff[ks];
      const char* pL = BsLb + laneAB + koff[ks];
      #pragma unroll
      for (int nf = 0; nf < 8; ++nf) {
        U8 bh, bl;
        bh.u = *(const u16x8*)(pH + nf * 4096);
        bl.u = *(const u16x8*)(pL + nf * 4096);
        acc[0][nf] = __builtin_amdgcn_mfma_f32_16x16x32_bf16(Ah[0][ks].b, bh.b, acc[0][nf], 0, 0, 0);
        acc[1][nf] = __builtin_amdgcn_mfma_f32_16x16x32_bf16(Ah[1][ks].b, bh.b, acc[1][nf], 0, 0, 0);
        acc[0][nf] = __builtin_amdgcn_mfma_f32_16x16x32_bf16(Al[0][ks].b, bh.b, acc[0][nf], 0, 0, 0);
        acc[1][nf] = __builtin_amdgcn_mfma_f32_16x16x32_bf16(Al[1][ks].b, bh.b, acc[1][nf], 0, 0, 0);
        acc[0][nf] = __builtin_amdgcn_mfma_f32_16x16x32_bf16(Ah[0][ks].b, bl.b, acc[0][nf], 0, 0, 0);
        acc[1][nf] = __builtin_amdgcn_mfma_f32_16x16x32_bf16(Ah[1][ks].b, bl.b, acc[1][nf], 0, 0, 0);
      }
    }

    // online epilogue: top-2/argmax + Z
    const int colbase = kt * 128 + l15;
    #pragma unroll
    for (int m = 0; m < 2; ++m)
      #pragma unroll
      for (int rg = 0; rg < 4; ++rg) {
        const int r = m * 4 + rg;
        float vv1 = v1[r], vv2 = v2[r];
        int kk1 = k1[r];
        const float mold = vv1;
        #pragma unroll
        for (int nf = 0; nf < 8; ++nf) {
          const float xv = acc[m][nf][rg];
          const int kk = colbase + nf * 16;
          const bool b = xv > vv1;
          vv2 = b ? vv1 : fmaxf(vv2, xv);
          kk1 = b ? kk : kk1;
          vv1 = b ? xv : vv1;
        }
        const float m200 = vv1 * 200.f;
        float z = rs[r] * __expf(fmaf(mold, 200.f, -m200));
        #pragma unroll
        for (int nf = 0; nf < 8; ++nf)
          z += __expf(fmaf(acc[m][nf][rg], 200.f, -m200));
        v1[r] = vv1; v2[r] = vv2; k1[r] = kk1; rs[r] = z;
      }
  }

  // cross-lane merge within each 16-lane group (lanes share rows across l15)
  #pragma unroll
  for (int m = 0; m < 2; ++m)
    #pragma unroll
    for (int rg = 0; rg < 4; ++rg) {
      const int r = m * 4 + rg;
      float a1 = v1[r], a2 = v2[r], az = rs[r];
      int ak = k1[r];
      #pragma unroll
      for (int off = 1; off <= 8; off <<= 1) {
        const float o1 = __shfl_xor(a1, off, 64);
        const float o2 = __shfl_xor(a2, off, 64);
        const float oz = __shfl_xor(az, off, 64);
        const int okk = __shfl_xor(ak, off, 64);
        const float nm = fmaxf(a1, o1);
        az = az * __expf((a1 - nm) * 200.f) + oz * __expf((o1 - nm) * 200.f);
        a2 = fmaxf(fminf(a1, o1), fmaxf(a2, o2));
        const bool take = (o1 > a1) || (o1 == a1 && okk < ak);
        ak = take ? okk : ak;
        a1 = nm;
      }
      if (l15 == 0) {
        const int row = row0 + w * 32 + m * 16 + hi * 4 + rg;
        rowV1[row] = a1; rowZ[row] = az; rowV2[row] = a2; rowK1[row] = ak;
      }
    }
}

// ---------------- MFMA pass 2: avg_probs column sums + sample-entropy ----------------

__global__ __launch_bounds__(256, 2) void k_pass2(const u16* __restrict__ xh, const u16* __restrict__ xl,
                                                  const u16* __restrict__ cbh, const u16* __restrict__ cbl,
                                                  const float* __restrict__ mask, const float* __restrict__ rowV1,
                                                  const float* __restrict__ rowZ, float* __restrict__ avgp,
                                                  float* __restrict__ t1g) {
  __shared__ __align__(16) char Bsmem[65536];
  __shared__ float ap[KCB];
  __shared__ float sm4[4];
  char* BsHb = Bsmem;
  char* BsLb = Bsmem + 32768;
  const int tid = threadIdx.x;
  const int lane = tid & 63, w = tid >> 6;
  const int l15 = lane & 15, hi = lane >> 4;
  const int row0 = blockIdx.x * 128;

  for (int i = tid; i < KCB; i += 256) ap[i] = 0.0f;

  const int tbase = ((tid >> 4) << 8) + ((((tid & 15) << 4)) ^ (((tid >> 4) & 7) << 4));

  U8 Ah[2][4], Al[2][4];
  #pragma unroll
  for (int mf = 0; mf < 2; ++mf) {
    const size_t arow = (size_t)(row0 + w * 32 + mf * 16 + l15);
    #pragma unroll
    for (int ks = 0; ks < 4; ++ks) {
      const size_t off = arow * DIMD + ks * 32 + hi * 8;
      Ah[mf][ks].u = *(const u16x8*)(xh + off);
      Al[mf][ks].u = *(const u16x8*)(xl + off);
    }
  }
  const int laneAB = l15 * 256;
  int koff[4];
  #pragma unroll
  for (int ks = 0; ks < 4; ++ks) koff[ks] = (ks * 64 + hi * 16) ^ ((l15 & 7) << 4);

  float m200r[8], zim[8];
  #pragma unroll
  for (int m = 0; m < 2; ++m)
    #pragma unroll
    for (int rg = 0; rg < 4; ++rg) {
      const int r = m * 4 + rg;
      const int row = row0 + w * 32 + m * 16 + hi * 4 + rg;
      m200r[r] = rowV1[row] * 200.f;
      zim[r] = mask[row] / rowZ[row];
    }
  float t1 = 0.0f;

  for (int kt = 0; kt < 16; ++kt) {
    __syncthreads();
    {
      const char* sH = (const char*)cbh + (size_t)kt * 32768;
      const char* sL = (const char*)cbl + (size_t)kt * 32768;
      #pragma unroll
      for (int i = 0; i < 8; ++i) {
        const int so = i * 4096 + tbase;
        const int ld = i * 4096 + w * 1024;
        __builtin_amdgcn_global_load_lds((const __attribute__((address_space(1))) void*)(sH + so),
                                         (__attribute__((address_space(3))) void*)(BsHb + ld), 16, 0, 0);
        __builtin_amdgcn_global_load_lds((const __attribute__((address_space(1))) void*)(sL + so),
                                         (__attribute__((address_space(3))) void*)(BsLb + ld), 16, 0, 0);
      }
    }
    __syncthreads();

    f32x4 acc[2][8];
    #pragma unroll
    for (int m = 0; m < 2; ++m)
      #pragma unroll
      for (int nf = 0; nf < 8; ++nf) acc[m][nf] = (f32x4){0.f, 0.f, 0.f, 0.f};

    #pragma unroll
    for (int ks = 0; ks < 4; ++ks) {
      const char* pH = BsHb + laneAB + koff[ks];
      const char* pL = BsLb + laneAB + koff[ks];
      #pragma unroll
      for (int nf = 0; nf < 8; ++nf) {
        U8 bh, bl;
        bh.u = *(const u16x8*)(pH + nf * 4096);
        bl.u = *(const u16x8*)(pL + nf * 4096);
        acc[0][nf] = __builtin_amdgcn_mfma_f32_16x16x32_bf16(Ah[0][ks].b, bh.b, acc[0][nf], 0, 0, 0);
        acc[1][nf] = __builtin_amdgcn_mfma_f32_16x16x32_bf16(Ah[1][ks].b, bh.b, acc[1][nf], 0, 0, 0);
        acc[0][nf] = __builtin_amdgcn_mfma_f32_16x16x32_bf16(Al[0][ks].b, bh.b, acc[0][nf], 0, 0, 0);
        acc[1][nf] = __builtin_amdgcn_mfma_f32_16x16x32_bf16(Al[1][ks].b, bh.b, acc[1][nf], 0, 0, 0);
        acc[0][nf] = __builtin_amdgcn_mfma_f32_16x16x32_bf16(Ah[0][ks].b, bl.b, acc[0][nf], 0, 0, 0);
        acc[1][nf] = __builtin_amdgcn_mfma_f32_16x16x32_bf16(Ah[1][ks].b, bl.b, acc[1][nf], 0, 0, 0);
      }
    }

    float colsum[8];
    #pragma unroll
    for (int nf = 0; nf < 8; ++nf) colsum[nf] = 0.0f;
    #pragma unroll
    for (int m = 0; m < 2; ++m)
      #pragma unroll
      for (int rg = 0; rg < 4; ++rg) {
        const int r = m * 4 + rg;
        #pragma unroll
        for (int nf = 0; nf < 8; ++nf) {
          const float u = fmaf(acc[m][nf][rg], 200.f, -m200r[r]);
          const float p = __expf(u) * zim[r];
          colsum[nf] += p;
          t1 = fmaf(p, u, t1);
        }
      }
    #pragma unroll
    for (int nf = 0; nf < 8; ++nf) {
      colsum[nf] += __shfl_xor(colsum[nf], 16, 64);
      colsum[nf] += __shfl_xor(colsum[nf], 32, 64);
    }
    if (lane < 16) {
      #pragma unroll
      for (int nf = 0; nf < 8; ++nf)
        atomicAdd(&ap[kt * 128 + nf * 16 + lane], colsum[nf]);
    }
  }

  __syncthreads();
  for (int i = tid; i < KCB; i += 256) atomicAdd(&avgp[i], ap[i]);
  #pragma unroll
  for (int off = 32; off; off >>= 1) t1 += __shfl_xor(t1, off, 64);
  if ((tid & 63) == 0) sm4[tid >> 6] = t1;
  __syncthreads();
  if (tid == 0) atomicAdd(t1g, sm4[0] + sm4[1] + sm4[2] + sm4[3]);
}

// ---------------- finalize scalars ----------------

__global__ __launch_bounds__(256) void k_final(const float* __restrict__ mask, const float* __restrict__ rowV1,
                                               const float* __restrict__ rowZ, const float* __restrict__ avgp,
                                               const float* __restrict__ t1g, float* __restrict__ out3) {
  __shared__ float sm[4];
  const int tid = threadIdx.x;
  float msum = 0.f, slogz = 0.f, slat = 0.f;
  for (int n = tid; n < NTOK; n += 256) {
    const float mk = mask[n];
    msum += mk;
    slogz = fmaf(mk, __logf(rowZ[n]), slogz);
    slat  = fmaf(mk, 2.0f - 2.0f * rowV1[n], slat);
  }
  msum = block_reduce4(msum, sm, tid);
  slogz = block_reduce4(slogz, sm, tid);
  slat = block_reduce4(slat, sm, tid);
  float ae = 0.f;
  for (int k2 = tid; k2 < KCB; k2 += 256) {
    const float a = avgp[k2] / msum;
    ae += a * __logf(a + 1e-5f);
  }
  ae = block_reduce4(ae, sm, tid);
  if (tid == 0) {
    const float t1 = t1g[0];
    const float sample_entropy = (slogz - t1) / msum;
    const float entropy = sample_entropy + ae;
    const float lat = slat / (msum + 1e-6f);
    out3[0] = lat;
    out3[1] = lat;
    out3[2] = entropy;
  }
}

// ---------------- launcher ----------------

extern "C" void kernel_launch(void* const* d_in, const int* in_sizes, int n_in,
                              void* d_out, int out_size, void* d_ws, size_t ws_size,
                              hipStream_t stream) {
  const float* x = (const float*)d_in[0];
  const float* mask = (const float*)d_in[1];
  const float* cb = (const float*)d_in[2];

  float* out = (float*)d_out;
  float* outQ = out;
  float* out3 = out + (size_t)NTOK * DIMD;
  float* outCnt = out3 + 3;
  float* outEnc = outCnt + KCB;

  // bf16-split x lives in the quantized output region until k_gather overwrites it
  u16* xh = (u16*)outQ;                      // NTOK*DIMD u16 (16 MB)
  u16* xl = xh + (size_t)NTOK * DIMD;        // next 16 MB

  float* ws = (float*)d_ws;
  float* scaleInv = ws;                       // N
  float* rowV1 = ws + NTOK;                   // N
  float* rowZ = ws + 2 * (size_t)NTOK;        // N
  float* rowV2 = ws + 3 * (size_t)NTOK;       // N
  int* rowIdx = (int*)(ws + 4 * (size_t)NTOK);// N
  float* avgp = ws + 5 * (size_t)NTOK;        // K
  float* t1g = avgp + KCB;                    // 1
  u16* cbh = (u16*)(ws + 5 * (size_t)NTOK + KCB + 4);  // K*D u16
  u16* cbl = cbh + (size_t)KCB * DIMD;

  int* rowK1 = rowIdx + NTOK;  // reuse: put K1 right after rowIdx? -- need separate N ints
  // NOTE: rowK1 placed after cbl to avoid overlap:
  rowK1 = (int*)(cbl + (size_t)KCB * DIMD);

  k_zero<<<(KCB + 255) / 256, 256, 0, stream>>>(avgp, t1g, outCnt);
  k_prepx<<<(NTOK * 64) / 256, 256, 0, stream>>>(x, mask, scaleInv, xh, xl);
  k_splitcb<<<(KCB * 64) / 256, 256, 0, stream>>>(cb, cbh, cbl);
  k_pass1<<<NTOK / 128, 256, 0, stream>>>(xh, xl, cbh, cbl, rowV1, rowZ, rowV2, rowK1);
  k_refine<<<(NTOK * 64) / 256, 256, 0, stream>>>(x, mask, cb, scaleInv, rowV1, rowV2, rowK1, rowIdx);
  k_pass2<<<NTOK / 128, 256, 0, stream>>>(xh, xl, cbh, cbl, mask, rowV1, rowZ, avgp, t1g);
  k_gather<<<(NTOK * 64) / 256, 256, 0, stream>>>(cb, mask, rowIdx, outQ, outCnt, outEnc);
  k_final<<<1, 256, 0, stream>>>(mask, rowV1, rowZ, avgp, t1g, out3);
}

// Round 3
// 380.236 us; speedup vs baseline: 2.7744x; 1.6157x over previous
//
#include <hip/hip_runtime.h>
#include <math.h>

#define NTOK 65536
#define DIMD 128
#define KCB  2048

typedef unsigned short u16;
typedef __attribute__((ext_vector_type(8))) unsigned short u16x8;
typedef __attribute__((ext_vector_type(8))) __bf16 bf16x8;
typedef __attribute__((ext_vector_type(4))) float f32x4;

union U8 { u16x8 u; bf16x8 b; };

__device__ __forceinline__ u16 f2bf(float f) {
  union { float f; unsigned u; } c; c.f = f;
  unsigned r = c.u + 0x7FFFu + ((c.u >> 16) & 1u);
  return (u16)(r >> 16);
}
__device__ __forceinline__ float bf2f(u16 h) {
  union { unsigned u; float f; } c; c.u = ((unsigned)h) << 16;
  return c.f;
}

__device__ __forceinline__ float block_reduce4(float v, volatile float* sm, int tid) {
  #pragma unroll
  for (int off = 32; off; off >>= 1) v += __shfl_xor(v, off, 64);
  __syncthreads();
  if ((tid & 63) == 0) sm[tid >> 6] = v;
  __syncthreads();
  float r = sm[0] + sm[1] + sm[2] + sm[3];
  __syncthreads();
  return r;
}

// ---------------- small kernels ----------------

__global__ __launch_bounds__(256) void k_zero(float* __restrict__ avgp, float* __restrict__ t1,
                                              float* __restrict__ acc3, float* __restrict__ cnt) {
  const int i = blockIdx.x * 256 + threadIdx.x;
  if (i < KCB) { avgp[i] = 0.0f; cnt[i] = 0.0f; }
  if (i == 0) { t1[0] = 0.0f; acc3[0] = 0.0f; acc3[1] = 0.0f; acc3[2] = 0.0f; }
}

// normalize rows of x and emit bf16 split halves (one wave per row)
__global__ __launch_bounds__(256) void k_prepx(const float* __restrict__ x, const float* __restrict__ mask,
                                               float* __restrict__ scaleInv, u16* __restrict__ xh,
                                               u16* __restrict__ xl) {
  const int wid = (blockIdx.x * 256 + threadIdx.x) >> 6;
  const int lane = threadIdx.x & 63;
  if (wid >= NTOK) return;
  const float add = (1.0f - mask[wid]) * 1e-6f;
  const float2 v = *(const float2*)(x + (size_t)wid * DIMD + lane * 2);
  const float a0 = v.x + add, a1 = v.y + add;
  float ss = a0 * a0 + a1 * a1;
  #pragma unroll
  for (int off = 32; off; off >>= 1) ss += __shfl_xor(ss, off, 64);
  const float sc = 1.0f / fmaxf(sqrtf(ss), 1e-6f);
  if (lane == 0) scaleInv[wid] = sc;
  const float f0 = a0 * sc, f1 = a1 * sc;
  const u16 h0 = f2bf(f0), h1 = f2bf(f1);
  const u16 g0 = f2bf(f0 - bf2f(h0)), g1 = f2bf(f1 - bf2f(h1));
  union { u16 s[2]; unsigned u; } wh, wl;
  wh.s[0] = h0; wh.s[1] = h1; wl.s[0] = g0; wl.s[1] = g1;
  *(unsigned*)(xh + (size_t)wid * DIMD + lane * 2) = wh.u;
  *(unsigned*)(xl + (size_t)wid * DIMD + lane * 2) = wl.u;
}

// split codebook rows to bf16 halves (one wave per code row)
__global__ __launch_bounds__(256) void k_splitcb(const float* __restrict__ cb, u16* __restrict__ cbh,
                                                 u16* __restrict__ cbl) {
  const int wid = (blockIdx.x * 256 + threadIdx.x) >> 6;
  const int lane = threadIdx.x & 63;
  if (wid >= KCB) return;
  const float2 v = *(const float2*)(cb + (size_t)wid * DIMD + lane * 2);
  const u16 h0 = f2bf(v.x), h1 = f2bf(v.y);
  const u16 g0 = f2bf(v.x - bf2f(h0)), g1 = f2bf(v.y - bf2f(h1));
  union { u16 s[2]; unsigned u; } wh, wl;
  wh.s[0] = h0; wh.s[1] = h1; wl.s[0] = g0; wl.s[1] = g1;
  *(unsigned*)(cbh + (size_t)wid * DIMD + lane * 2) = wh.u;
  *(unsigned*)(cbl + (size_t)wid * DIMD + lane * 2) = wl.u;
}

__global__ __launch_bounds__(256) void k_gather(const float* __restrict__ cb, const float* __restrict__ mask,
                                                const int* __restrict__ rowIdx, float* __restrict__ outQ,
                                                float* __restrict__ outCnt, float* __restrict__ outEnc) {
  const int g = blockIdx.x * 256 + threadIdx.x;
  const int row = g >> 5, l = g & 31;
  if (row >= NTOK) return;
  const int idx = rowIdx[row];
  const float4 v = *(const float4*)(cb + (size_t)idx * DIMD + l * 4);
  *(float4*)(outQ + (size_t)row * DIMD + l * 4) = v;
  if (l == 0) {
    atomicAdd(&outCnt[idx], mask[row]);
    outEnc[row] = (float)idx;
  }
}

// exact-f32 argmax rescan for rows whose approx top-2 gap is tiny.
// lane-parallel over k: x-row in registers, 1 cross-lane reduce at the end.
__global__ __launch_bounds__(256) void k_refine(const float* __restrict__ x, const float* __restrict__ mask,
                                                const float* __restrict__ cb, const float* __restrict__ scaleInv,
                                                const float* __restrict__ rowV1, const float* __restrict__ rowV2,
                                                int* __restrict__ rowIdx) {
  const int wid = (blockIdx.x * 256 + threadIdx.x) >> 6;
  const int lane = threadIdx.x & 63;
  if (wid >= NTOK) return;
  if (rowV1[wid] - rowV2[wid] > 1e-4f) return;  // wave-uniform branch
  const float add = (1.0f - mask[wid]) * 1e-6f;
  const float sc = scaleInv[wid];
  float4 xr[32];
  #pragma unroll
  for (int q = 0; q < 32; ++q) {
    const float4 t = *(const float4*)(x + (size_t)wid * DIMD + q * 4);
    xr[q].x = (t.x + add) * sc; xr[q].y = (t.y + add) * sc;
    xr[q].z = (t.z + add) * sc; xr[q].w = (t.w + add) * sc;
  }
  float best = -1e30f;
  int bidx = 0;
  for (int k = lane; k < KCB; k += 64) {
    const float4* crow = (const float4*)(cb + (size_t)k * DIMD);
    float d0 = 0.f, d1 = 0.f;
    #pragma unroll
    for (int q = 0; q < 32; q += 2) {
      const float4 c0 = crow[q];
      const float4 c1 = crow[q + 1];
      d0 = fmaf(c0.x, xr[q].x, d0);     d0 = fmaf(c0.y, xr[q].y, d0);
      d0 = fmaf(c0.z, xr[q].z, d0);     d0 = fmaf(c0.w, xr[q].w, d0);
      d1 = fmaf(c1.x, xr[q + 1].x, d1); d1 = fmaf(c1.y, xr[q + 1].y, d1);
      d1 = fmaf(c1.z, xr[q + 1].z, d1); d1 = fmaf(c1.w, xr[q + 1].w, d1);
    }
    const float d = d0 + d1;
    if (d > best) { best = d; bidx = k; }  // ascending k per lane -> first max kept
  }
  #pragma unroll
  for (int off = 32; off; off >>= 1) {
    const float ob = __shfl_xor(best, off, 64);
    const int oi = __shfl_xor(bidx, off, 64);
    if (ob > best || (ob == best && oi < bidx)) { best = ob; bidx = oi; }
  }
  if (lane == 0) rowIdx[wid] = bidx;
}

// ---------------- MFMA pass 1: per-row max / argmax(top2) / Z ----------------

__global__ __launch_bounds__(256, 2) void k_pass1(const u16* __restrict__ xh, const u16* __restrict__ xl,
                                                  const u16* __restrict__ cbh, const u16* __restrict__ cbl,
                                                  float* __restrict__ rowV1, float* __restrict__ rowZ,
                                                  float* __restrict__ rowV2, int* __restrict__ rowIdx) {
  __shared__ __align__(16) char Bsmem[65536];
  char* BsHb = Bsmem;
  char* BsLb = Bsmem + 32768;
  const int tid = threadIdx.x;
  const int lane = tid & 63, w = tid >> 6;
  const int l15 = lane & 15, hi = lane >> 4;
  const int row0 = blockIdx.x * 128;

  // staging source offset (inverse-swizzled so that linear LDS dest + swizzled read works)
  const int tbase = ((tid >> 4) << 8) + ((((tid & 15) << 4)) ^ (((tid >> 4) & 7) << 4));

  // A fragments in registers, reused for all 16 k-tiles
  U8 Ah[2][4], Al[2][4];
  #pragma unroll
  for (int mf = 0; mf < 2; ++mf) {
    const size_t arow = (size_t)(row0 + w * 32 + mf * 16 + l15);
    #pragma unroll
    for (int ks = 0; ks < 4; ++ks) {
      const size_t off = arow * DIMD + ks * 32 + hi * 8;
      Ah[mf][ks].u = *(const u16x8*)(xh + off);
      Al[mf][ks].u = *(const u16x8*)(xl + off);
    }
  }
  const int laneAB = l15 * 256;
  int koff[4];
  #pragma unroll
  for (int ks = 0; ks < 4; ++ks) koff[ks] = (ks * 64 + hi * 16) ^ ((l15 & 7) << 4);

  float v1[8], v2[8], rs[8];
  int k1[8];
  #pragma unroll
  for (int r = 0; r < 8; ++r) { v1[r] = -1e30f; v2[r] = -1e30f; rs[r] = 0.0f; k1[r] = 0; }

  for (int kt = 0; kt < 16; ++kt) {
    __syncthreads();
    {
      const char* sH = (const char*)cbh + (size_t)kt * 32768;
      const char* sL = (const char*)cbl + (size_t)kt * 32768;
      #pragma unroll
      for (int i = 0; i < 8; ++i) {
        const int so = i * 4096 + tbase;
        const int ld = i * 4096 + w * 1024;
        __builtin_amdgcn_global_load_lds((const __attribute__((address_space(1))) void*)(sH + so),
                                         (__attribute__((address_space(3))) void*)(BsHb + ld), 16, 0, 0);
        __builtin_amdgcn_global_load_lds((const __attribute__((address_space(1))) void*)(sL + so),
                                         (__attribute__((address_space(3))) void*)(BsLb + ld), 16, 0, 0);
      }
    }
    __syncthreads();

    f32x4 acc[2][8];
    #pragma unroll
    for (int m = 0; m < 2; ++m)
      #pragma unroll
      for (int nf = 0; nf < 8; ++nf) acc[m][nf] = (f32x4){0.f, 0.f, 0.f, 0.f};

    #pragma unroll
    for (int ks = 0; ks < 4; ++ks) {
      const char* pH = BsHb + laneAB + koff[ks];
      const char* pL = BsLb + laneAB + koff[ks];
      #pragma unroll
      for (int nf = 0; nf < 8; ++nf) {
        U8 bh, bl;
        bh.u = *(const u16x8*)(pH + nf * 4096);
        bl.u = *(const u16x8*)(pL + nf * 4096);
        acc[0][nf] = __builtin_amdgcn_mfma_f32_16x16x32_bf16(Ah[0][ks].b, bh.b, acc[0][nf], 0, 0, 0);
        acc[1][nf] = __builtin_amdgcn_mfma_f32_16x16x32_bf16(Ah[1][ks].b, bh.b, acc[1][nf], 0, 0, 0);
        acc[0][nf] = __builtin_amdgcn_mfma_f32_16x16x32_bf16(Al[0][ks].b, bh.b, acc[0][nf], 0, 0, 0);
        acc[1][nf] = __builtin_amdgcn_mfma_f32_16x16x32_bf16(Al[1][ks].b, bh.b, acc[1][nf], 0, 0, 0);
        acc[0][nf] = __builtin_amdgcn_mfma_f32_16x16x32_bf16(Ah[0][ks].b, bl.b, acc[0][nf], 0, 0, 0);
        acc[1][nf] = __builtin_amdgcn_mfma_f32_16x16x32_bf16(Ah[1][ks].b, bl.b, acc[1][nf], 0, 0, 0);
      }
    }

    // online epilogue: top-2/argmax + Z
    const int colbase = kt * 128 + l15;
    #pragma unroll
    for (int m = 0; m < 2; ++m)
      #pragma unroll
      for (int rg = 0; rg < 4; ++rg) {
        const int r = m * 4 + rg;
        float vv1 = v1[r], vv2 = v2[r];
        int kk1 = k1[r];
        const float mold = vv1;
        #pragma unroll
        for (int nf = 0; nf < 8; ++nf) {
          const float xv = acc[m][nf][rg];
          const int kk = colbase + nf * 16;
          const bool b = xv > vv1;
          vv2 = b ? vv1 : fmaxf(vv2, xv);
          kk1 = b ? kk : kk1;
          vv1 = b ? xv : vv1;
        }
        const float m200 = vv1 * 200.f;
        float z = rs[r] * __expf(fmaf(mold, 200.f, -m200));
        #pragma unroll
        for (int nf = 0; nf < 8; ++nf)
          z += __expf(fmaf(acc[m][nf][rg], 200.f, -m200));
        v1[r] = vv1; v2[r] = vv2; k1[r] = kk1; rs[r] = z;
      }
  }

  // cross-lane merge within each 16-lane group (lanes share rows across l15)
  #pragma unroll
  for (int m = 0; m < 2; ++m)
    #pragma unroll
    for (int rg = 0; rg < 4; ++rg) {
      const int r = m * 4 + rg;
      float a1 = v1[r], a2 = v2[r], az = rs[r];
      int ak = k1[r];
      #pragma unroll
      for (int off = 1; off <= 8; off <<= 1) {
        const float o1 = __shfl_xor(a1, off, 64);
        const float o2 = __shfl_xor(a2, off, 64);
        const float oz = __shfl_xor(az, off, 64);
        const int okk = __shfl_xor(ak, off, 64);
        const float nm = fmaxf(a1, o1);
        az = az * __expf((a1 - nm) * 200.f) + oz * __expf((o1 - nm) * 200.f);
        a2 = fmaxf(fminf(a1, o1), fmaxf(a2, o2));
        const bool take = (o1 > a1) || (o1 == a1 && okk < ak);
        ak = take ? okk : ak;
        a1 = nm;
      }
      if (l15 == 0) {
        const int row = row0 + w * 32 + m * 16 + hi * 4 + rg;
        rowV1[row] = a1; rowZ[row] = az; rowV2[row] = a2; rowIdx[row] = ak;
      }
    }
}

// ---------------- MFMA pass 2: avg_probs column sums + sample-entropy ----------------

__global__ __launch_bounds__(256, 2) void k_pass2(const u16* __restrict__ xh, const u16* __restrict__ xl,
                                                  const u16* __restrict__ cbh, const u16* __restrict__ cbl,
                                                  const float* __restrict__ mask, const float* __restrict__ rowV1,
                                                  const float* __restrict__ rowZ, float* __restrict__ avgp,
                                                  float* __restrict__ t1g) {
  __shared__ __align__(16) char Bsmem[65536];
  __shared__ float ap[KCB];
  __shared__ float sm4[4];
  char* BsHb = Bsmem;
  char* BsLb = Bsmem + 32768;
  const int tid = threadIdx.x;
  const int lane = tid & 63, w = tid >> 6;
  const int l15 = lane & 15, hi = lane >> 4;
  const int row0 = blockIdx.x * 128;

  for (int i = tid; i < KCB; i += 256) ap[i] = 0.0f;

  const int tbase = ((tid >> 4) << 8) + ((((tid & 15) << 4)) ^ (((tid >> 4) & 7) << 4));

  U8 Ah[2][4], Al[2][4];
  #pragma unroll
  for (int mf = 0; mf < 2; ++mf) {
    const size_t arow = (size_t)(row0 + w * 32 + mf * 16 + l15);
    #pragma unroll
    for (int ks = 0; ks < 4; ++ks) {
      const size_t off = arow * DIMD + ks * 32 + hi * 8;
      Ah[mf][ks].u = *(const u16x8*)(xh + off);
      Al[mf][ks].u = *(const u16x8*)(xl + off);
    }
  }
  const int laneAB = l15 * 256;
  int koff[4];
  #pragma unroll
  for (int ks = 0; ks < 4; ++ks) koff[ks] = (ks * 64 + hi * 16) ^ ((l15 & 7) << 4);

  float m200r[8], zim[8];
  #pragma unroll
  for (int m = 0; m < 2; ++m)
    #pragma unroll
    for (int rg = 0; rg < 4; ++rg) {
      const int r = m * 4 + rg;
      const int row = row0 + w * 32 + m * 16 + hi * 4 + rg;
      m200r[r] = rowV1[row] * 200.f;
      zim[r] = mask[row] / rowZ[row];
    }
  float t1 = 0.0f;

  for (int kt = 0; kt < 16; ++kt) {
    __syncthreads();
    {
      const char* sH = (const char*)cbh + (size_t)kt * 32768;
      const char* sL = (const char*)cbl + (size_t)kt * 32768;
      #pragma unroll
      for (int i = 0; i < 8; ++i) {
        const int so = i * 4096 + tbase;
        const int ld = i * 4096 + w * 1024;
        __builtin_amdgcn_global_load_lds((const __attribute__((address_space(1))) void*)(sH + so),
                                         (__attribute__((address_space(3))) void*)(BsHb + ld), 16, 0, 0);
        __builtin_amdgcn_global_load_lds((const __attribute__((address_space(1))) void*)(sL + so),
                                         (__attribute__((address_space(3))) void*)(BsLb + ld), 16, 0, 0);
      }
    }
    __syncthreads();

    f32x4 acc[2][8];
    #pragma unroll
    for (int m = 0; m < 2; ++m)
      #pragma unroll
      for (int nf = 0; nf < 8; ++nf) acc[m][nf] = (f32x4){0.f, 0.f, 0.f, 0.f};

    #pragma unroll
    for (int ks = 0; ks < 4; ++ks) {
      const char* pH = BsHb + laneAB + koff[ks];
      const char* pL = BsLb + laneAB + koff[ks];
      #pragma unroll
      for (int nf = 0; nf < 8; ++nf) {
        U8 bh, bl;
        bh.u = *(const u16x8*)(pH + nf * 4096);
        bl.u = *(const u16x8*)(pL + nf * 4096);
        acc[0][nf] = __builtin_amdgcn_mfma_f32_16x16x32_bf16(Ah[0][ks].b, bh.b, acc[0][nf], 0, 0, 0);
        acc[1][nf] = __builtin_amdgcn_mfma_f32_16x16x32_bf16(Ah[1][ks].b, bh.b, acc[1][nf], 0, 0, 0);
        acc[0][nf] = __builtin_amdgcn_mfma_f32_16x16x32_bf16(Al[0][ks].b, bh.b, acc[0][nf], 0, 0, 0);
        acc[1][nf] = __builtin_amdgcn_mfma_f32_16x16x32_bf16(Al[1][ks].b, bh.b, acc[1][nf], 0, 0, 0);
        acc[0][nf] = __builtin_amdgcn_mfma_f32_16x16x32_bf16(Ah[0][ks].b, bl.b, acc[0][nf], 0, 0, 0);
        acc[1][nf] = __builtin_amdgcn_mfma_f32_16x16x32_bf16(Ah[1][ks].b, bl.b, acc[1][nf], 0, 0, 0);
      }
    }

    float colsum[8];
    #pragma unroll
    for (int nf = 0; nf < 8; ++nf) colsum[nf] = 0.0f;
    #pragma unroll
    for (int m = 0; m < 2; ++m)
      #pragma unroll
      for (int rg = 0; rg < 4; ++rg) {
        const int r = m * 4 + rg;
        #pragma unroll
        for (int nf = 0; nf < 8; ++nf) {
          const float u = fmaf(acc[m][nf][rg], 200.f, -m200r[r]);
          const float p = __expf(u) * zim[r];
          colsum[nf] += p;
          t1 = fmaf(p, u, t1);
        }
      }
    #pragma unroll
    for (int nf = 0; nf < 8; ++nf) {
      colsum[nf] += __shfl_xor(colsum[nf], 16, 64);
      colsum[nf] += __shfl_xor(colsum[nf], 32, 64);
    }
    if (lane < 16) {
      #pragma unroll
      for (int nf = 0; nf < 8; ++nf)
        atomicAdd(&ap[kt * 128 + nf * 16 + lane], colsum[nf]);
    }
  }

  __syncthreads();
  for (int i = tid; i < KCB; i += 256) atomicAdd(&avgp[i], ap[i]);
  #pragma unroll
  for (int off = 32; off; off >>= 1) t1 += __shfl_xor(t1, off, 64);
  if ((tid & 63) == 0) sm4[tid >> 6] = t1;
  __syncthreads();
  if (tid == 0) atomicAdd(t1g, sm4[0] + sm4[1] + sm4[2] + sm4[3]);
}

// ---------------- scalar reductions ----------------

__global__ __launch_bounds__(256) void k_stats(const float* __restrict__ mask, const float* __restrict__ rowV1,
                                               const float* __restrict__ rowZ, float* __restrict__ acc3) {
  __shared__ float sm[4];
  const int tid = threadIdx.x;
  float msum = 0.f, slogz = 0.f, slat = 0.f;
  for (int n = blockIdx.x * 256 + tid; n < NTOK; n += gridDim.x * 256) {
    const float mk = mask[n];
    msum += mk;
    slogz = fmaf(mk, __logf(rowZ[n]), slogz);
    slat  = fmaf(mk, 2.0f - 2.0f * rowV1[n], slat);
  }
  msum = block_reduce4(msum, sm, tid);
  slogz = block_reduce4(slogz, sm, tid);
  slat = block_reduce4(slat, sm, tid);
  if (tid == 0) {
    atomicAdd(&acc3[0], msum);
    atomicAdd(&acc3[1], slogz);
    atomicAdd(&acc3[2], slat);
  }
}

__global__ __launch_bounds__(256) void k_final(const float* __restrict__ avgp, const float* __restrict__ t1g,
                                               const float* __restrict__ acc3, float* __restrict__ out3) {
  __shared__ float sm[4];
  const int tid = threadIdx.x;
  const float msum = acc3[0];
  float ae = 0.f;
  for (int k2 = tid; k2 < KCB; k2 += 256) {
    const float a = avgp[k2] / msum;
    ae += a * __logf(a + 1e-5f);
  }
  ae = block_reduce4(ae, sm, tid);
  if (tid == 0) {
    const float sample_entropy = (acc3[1] - t1g[0]) / msum;
    const float lat = acc3[2] / (msum + 1e-6f);
    out3[0] = lat;
    out3[1] = lat;
    out3[2] = sample_entropy + ae;
  }
}

// ---------------- launcher ----------------

extern "C" void kernel_launch(void* const* d_in, const int* in_sizes, int n_in,
                              void* d_out, int out_size, void* d_ws, size_t ws_size,
                              hipStream_t stream) {
  const float* x = (const float*)d_in[0];
  const float* mask = (const float*)d_in[1];
  const float* cb = (const float*)d_in[2];

  float* out = (float*)d_out;
  float* outQ = out;
  float* out3 = out + (size_t)NTOK * DIMD;
  float* outCnt = out3 + 3;
  float* outEnc = outCnt + KCB;

  // bf16-split x lives in the quantized output region until k_gather overwrites it
  u16* xh = (u16*)outQ;                      // NTOK*DIMD u16 (16 MB)
  u16* xl = xh + (size_t)NTOK * DIMD;        // next 16 MB

  float* ws = (float*)d_ws;
  float* scaleInv = ws;                       // N
  float* rowV1 = ws + NTOK;                   // N
  float* rowZ = ws + 2 * (size_t)NTOK;        // N
  float* rowV2 = ws + 3 * (size_t)NTOK;       // N
  int* rowIdx = (int*)(ws + 4 * (size_t)NTOK);// N
  float* avgp = ws + 5 * (size_t)NTOK;        // K
  float* t1g = avgp + KCB;                    // 1
  float* acc3 = t1g + 1;                      // 3
  u16* cbh = (u16*)(ws + 5 * (size_t)NTOK + KCB + 8);  // K*D u16
  u16* cbl = cbh + (size_t)KCB * DIMD;

  k_zero<<<(KCB + 255) / 256, 256, 0, stream>>>(avgp, t1g, acc3, outCnt);
  k_prepx<<<(NTOK * 64) / 256, 256, 0, stream>>>(x, mask, scaleInv, xh, xl);
  k_splitcb<<<(KCB * 64) / 256, 256, 0, stream>>>(cb, cbh, cbl);
  k_pass1<<<NTOK / 128, 256, 0, stream>>>(xh, xl, cbh, cbl, rowV1, rowZ, rowV2, rowIdx);
  k_refine<<<(NTOK * 64) / 256, 256, 0, stream>>>(x, mask, cb, scaleInv, rowV1, rowV2, rowIdx);
  k_pass2<<<NTOK / 128, 256, 0, stream>>>(xh, xl, cbh, cbl, mask, rowV1, rowZ, avgp, t1g);
  k_stats<<<64, 256, 0, stream>>>(mask, rowV1, rowZ, acc3);
  k_gather<<<(NTOK * 32) / 256, 256, 0, stream>>>(cb, mask, rowIdx, outQ, outCnt, outEnc);
  k_final<<<1, 256, 0, stream>>>(avgp, t1g, acc3, out3);
}